// Round 2
// baseline (756.562 us; speedup 1.0000x reference)
//
#include <hip/hip_runtime.h>

// QuietSTaR forward, round 2.
// Changes vs round 1:
//  - GEMM staging via __builtin_amdgcn_global_load_lds (width 16), fragment-
//    major LDS layout -> conflict-free ds_read_b128 (2-way only, free).
//  - Base-logits GEMM fuses entropy partials (sum e^x, sum x e^x) via
//    shfl-reduce + atomicAdd; logits never materialized (no-max exp is safe:
//    |logit| < ~0.1). Final GEMM fuses sum e^x (lse) + label gather.
//  - thoughts+mix fused (no tmean round-trip).
//  - 64x64-tile GEMM variant for H x H GEMMs (256 blocks).
//  - 64x64 float4/LDS transpose for weight prep.
// B=4 S=256 V=32000 H=1024 K=4 T=20; M=1024.

#define V_SZ 32000
#define H_SZ 1024
#define S_SZ 256
#define B_SZ 4
#define M_SZ 1024
#define K_TH 4
#define T_TH 20

typedef __bf16 bf16_t;
typedef __bf16 bf16x8 __attribute__((ext_vector_type(8)));
typedef __bf16 bf16x4 __attribute__((ext_vector_type(4)));
typedef float  f32x4  __attribute__((ext_vector_type(4)));

__device__ __forceinline__ float tanh_fast(float x) {
  x = fminf(fmaxf(x, -15.f), 15.f);
  float e = __expf(2.f * x);
  return (e - 1.f) / (e + 1.f);
}
__device__ __forceinline__ float sigmoid_f(float x) {
  return 1.f / (1.f + __expf(-x));
}

// async global->LDS DMA, 16 B per lane; LDS dest = base + lane*16
__device__ __forceinline__ void async_load16(const void* g, void* l) {
  __builtin_amdgcn_global_load_lds(
      (const __attribute__((address_space(1))) unsigned int*)g,
      (__attribute__((address_space(3))) unsigned int*)l, 16, 0, 0);
}

// ---------------- transpose + cast fp32 (R,C) -> bf16 (C,R), 64x64 tiles ----
__global__ void __launch_bounds__(256) transpose_cast_kernel(
    const float* __restrict__ in, bf16_t* __restrict__ out, int R, int C) {
  __shared__ float tile[64][65];
  const int t = threadIdx.x;
  const int c0 = blockIdx.x << 6, r0 = blockIdx.y << 6;
  const int tx = t & 15, ty = t >> 4;
  #pragma unroll
  for (int rr = 0; rr < 4; ++rr) {
    const float4 v = *(const float4*)(in + (size_t)(r0 + ty + rr * 16) * C + c0 + tx * 4);
    float* dst = &tile[ty + rr * 16][tx * 4];
    dst[0] = v.x; dst[1] = v.y; dst[2] = v.z; dst[3] = v.w;
  }
  __syncthreads();
  const int cc = t >> 2, rg = t & 3;   // out row c0+cc, 16 cols starting r0+rg*16
  bf16_t tmp[16];
  #pragma unroll
  for (int jj = 0; jj < 16; ++jj) tmp[jj] = (bf16_t)tile[rg * 16 + jj][cc];
  bf16_t* o = out + (size_t)(c0 + cc) * R + r0 + rg * 16;
  *(bf16x8*)(o)     = *(bf16x8*)(tmp);
  *(bf16x8*)(o + 8) = *(bf16x8*)(tmp + 8);
}

// ---------------- embed row gather + cast to bf16 ----------------
__global__ void __launch_bounds__(256) gather_cast_kernel(
    const int* __restrict__ ids, const float* __restrict__ embed,
    bf16_t* __restrict__ X0) {
  const int i = blockIdx.x * 256 + threadIdx.x;   // over M*H/4
  const int m = i >> 8, c4 = (i & 255) << 2;
  const float4 v = *(const float4*)(embed + (size_t)ids[m] * H_SZ + c4);
  bf16x4 o;
  o[0] = (bf16_t)v.x; o[1] = (bf16_t)v.y; o[2] = (bf16_t)v.z; o[3] = (bf16_t)v.w;
  *(bf16x4*)(X0 + (size_t)m * H_SZ + c4) = o;
}

// ---------------- bf16 MFMA GEMM: C(M,N) = A(M,1024) @ BT(N,1024)^T ---------
// FR: fragments per dim per wave (2 -> 64-tile, 4 -> 128-tile)
// EPI 1: v=tanh(acc+bias[n]); outF=v; outB=bf16(v)      (hidden)
// EPI 2: outF=tanh(acc)                                 (g)
// EPI 3: entropy partials only: pZ[m]+=sum e^x, pS[m]+=sum x e^x (no store)
// EPI 4: outF=acc (fp32 logits), pZ[m]+=sum e^x, picked[m]=acc at labels[m+1]
template <int EPI, int FR>
__global__ void __launch_bounds__(256) gemm_bt(
    const bf16_t* __restrict__ A, const bf16_t* __restrict__ BT,
    float* __restrict__ outF, bf16_t* __restrict__ outB,
    const float* __restrict__ bias, const int* __restrict__ labels,
    float* __restrict__ pZ, float* __restrict__ pS, float* __restrict__ picked,
    int mtiles, int ntiles, int N) {
  constexpr int BMN = FR * 32;          // 64 or 128
  constexpr int GRP = 2 * FR;           // 16-row groups per matrix
  __shared__ __align__(16) bf16_t As[GRP * 512];
  __shared__ __align__(16) bf16_t Bs[GRP * 512];
  const int t = threadIdx.x;
  const int x = blockIdx.x & 7, y = blockIdx.x >> 3;
  const int tm = y % mtiles, tn = x + 8 * (y / mtiles);
  if (tn >= ntiles) return;
  const int m0 = tm * BMN, n0 = tn * BMN;
  const int lane = t & 63, wv = t >> 6, wm = wv >> 1, wn = wv & 1;
  const int col = lane & 15, qd = lane >> 4;
  // DMA source: lane l covers (row-in-group = l&15, kchunk = l>>4)
  const int lrow = lane & 15, lkc = lane >> 4;
  const bf16_t* gA[FR / 2];
  const bf16_t* gB[FR / 2];
  #pragma unroll
  for (int j = 0; j < FR / 2; ++j) {
    const int g = wv * (FR / 2) + j;
    gA[j] = A  + (size_t)(m0 + g * 16 + lrow) * 1024 + lkc * 8;
    gB[j] = BT + (size_t)(n0 + g * 16 + lrow) * 1024 + lkc * 8;
  }
  f32x4 acc[FR][FR] = {};
  for (int kb = 0; kb < 1024; kb += 32) {
    #pragma unroll
    for (int j = 0; j < FR / 2; ++j) {
      const int g = wv * (FR / 2) + j;
      async_load16(gA[j] + kb, As + g * 512);
      async_load16(gB[j] + kb, Bs + g * 512);
    }
    __syncthreads();
    bf16x8 af[FR], bg[FR];
    #pragma unroll
    for (int mi = 0; mi < FR; ++mi)
      af[mi] = *(const bf16x8*)(As + (wm * FR + mi) * 512 + qd * 128 + col * 8);
    #pragma unroll
    for (int ni = 0; ni < FR; ++ni)
      bg[ni] = *(const bf16x8*)(Bs + (wn * FR + ni) * 512 + qd * 128 + col * 8);
    #pragma unroll
    for (int mi = 0; mi < FR; ++mi)
      #pragma unroll
      for (int ni = 0; ni < FR; ++ni)
        acc[mi][ni] = __builtin_amdgcn_mfma_f32_16x16x32_bf16(
            af[mi], bg[ni], acc[mi][ni], 0, 0, 0);
    __syncthreads();
  }
  // ---- epilogues; D row = qd*4+r, col = lane&15 ----
  if (EPI == 1 || EPI == 2) {
    #pragma unroll
    for (int mi = 0; mi < FR; ++mi) {
      #pragma unroll
      for (int ni = 0; ni < FR; ++ni) {
        const int gm = m0 + wm * FR * 16 + mi * 16 + qd * 4;
        const int gn = n0 + wn * FR * 16 + ni * 16 + col;
        #pragma unroll
        for (int r = 0; r < 4; ++r) {
          const size_t o = (size_t)(gm + r) * N + gn;
          float v = acc[mi][ni][r];
          if (EPI == 1) {
            v = tanh_fast(v + bias[gn]);
            outF[o] = v;
            outB[o] = (bf16_t)v;
          } else {
            outF[o] = tanh_fast(v);
          }
        }
      }
    }
  } else if (EPI == 3) {
    #pragma unroll
    for (int mi = 0; mi < FR; ++mi) {
      #pragma unroll
      for (int r = 0; r < 4; ++r) {
        float ez = 0.f, es = 0.f;
        #pragma unroll
        for (int ni = 0; ni < FR; ++ni) {
          const float v = acc[mi][ni][r];
          const float e = __expf(v);
          ez += e; es += v * e;
        }
        #pragma unroll
        for (int msk = 8; msk >= 1; msk >>= 1) {
          ez += __shfl_xor(ez, msk, 64);
          es += __shfl_xor(es, msk, 64);
        }
        if (col == 0) {
          const int row = m0 + wm * FR * 16 + mi * 16 + qd * 4 + r;
          atomicAdd(&pZ[row], ez);
          atomicAdd(&pS[row], es);
        }
      }
    }
  } else {  // EPI == 4
    #pragma unroll
    for (int mi = 0; mi < FR; ++mi) {
      #pragma unroll
      for (int r = 0; r < 4; ++r) {
        const int row = m0 + wm * FR * 16 + mi * 16 + qd * 4 + r;
        const int lab = ((row & 255) != 255) ? labels[row + 1] : -1;
        float ez = 0.f;
        #pragma unroll
        for (int ni = 0; ni < FR; ++ni) {
          const int gn = n0 + wn * FR * 16 + ni * 16 + col;
          const float v = acc[mi][ni][r];
          outF[(size_t)row * N + gn] = v;
          ez += __expf(v);
          if (gn == lab) picked[row] = v;
        }
        #pragma unroll
        for (int msk = 8; msk >= 1; msk >>= 1) ez += __shfl_xor(ez, msk, 64);
        if (col == 0) atomicAdd(&pZ[row], ez);
      }
    }
  }
}

// ---------------- inject[s] from entropy partials ----------------
__global__ void __launch_bounds__(256) inject_kernel(
    const float* __restrict__ pZ, const float* __restrict__ pS,
    int* __restrict__ inject) {
  const int s = threadIdx.x;  // S == 256
  float e = 0.f;
  #pragma unroll
  for (int b = 0; b < B_SZ; ++b) {
    const int m = b * S_SZ + s;
    const float Z = pZ[m];
    e += __logf(Z) - pS[m] / Z;   // logZ - S/Z = entropy (natural log)
  }
  e *= 0.25f * (1.0f / 10.373491f);  // /B /ln(V)
  inject[s] = (e > 0.6f && s < S_SZ - 1) ? 1 : 0;
}

// ---------------- fused thoughts + scorer + mix + enhanced (bf16) -----------
__device__ __forceinline__ float block_sum(float v, float* red, int t) {
  #pragma unroll
  for (int m = 32; m >= 1; m >>= 1) v += __shfl_xor(v, m, 64);
  __syncthreads();
  if ((t & 63) == 0) red[t >> 6] = v;
  __syncthreads();
  return red[0] + red[1] + red[2] + red[3];
}

__global__ void __launch_bounds__(256) mix_kernel(
    const float* __restrict__ hidden, const float* __restrict__ gF,
    const float* __restrict__ thE, const float* __restrict__ tpos,
    const float* __restrict__ wsc, const float* __restrict__ wgt,
    const int* __restrict__ inject, bf16_t* __restrict__ enhB) {
  const int m = blockIdx.x, t = threadIdx.x, s = m & (S_SZ - 1);
  __shared__ float red[4];
  float hv[4], tmv[4][4], ws1[4], ws2[4], wg1[4], wg2[4];
  #pragma unroll
  for (int j = 0; j < 4; ++j) {
    const int h = t + 256 * j;
    hv[j]  = hidden[(size_t)m * H_SZ + h];
    ws1[j] = wsc[h];  ws2[j] = wsc[H_SZ + h];
    wg1[j] = wgt[h];  wg2[j] = wgt[H_SZ + h];
    const float gb = gF[(size_t)m * H_SZ + h];
    float tp[T_TH];
    #pragma unroll
    for (int tt = 0; tt < T_TH; ++tt) tp[tt] = tpos[tt * H_SZ + h];
    #pragma unroll
    for (int k = 0; k < K_TH; ++k) {
      const float base = gb + thE[k * H_SZ + h];
      float sum = 0.f;
      #pragma unroll
      for (int tt = 0; tt < T_TH; ++tt) sum += tanh_fast(base + tp[tt]);
      tmv[k][j] = sum * (1.f / T_TH);
    }
  }
  float ph = 0.f, pg = 0.f;
  #pragma unroll
  for (int j = 0; j < 4; ++j) { ph += hv[j] * ws1[j]; pg += hv[j] * wg1[j]; }
  const float sh = block_sum(ph, red, t);
  const float gh = block_sum(pg, red, t);
  float comp[4];
  #pragma unroll
  for (int k = 0; k < K_TH; ++k) {
    float pc = 0.f;
    #pragma unroll
    for (int j = 0; j < 4; ++j) pc += tmv[k][j] * ws2[j];
    comp[k] = sigmoid_f(sh + block_sum(pc, red, t));
  }
  const float ma = fmaxf(fmaxf(comp[0], comp[1]), fmaxf(comp[2], comp[3]));
  float al[4], asum = 0.f;
  #pragma unroll
  for (int k = 0; k < K_TH; ++k) { al[k] = __expf(comp[k] - ma); asum += al[k]; }
  const float inv = 1.f / asum;
  float mx[4];
  #pragma unroll
  for (int j = 0; j < 4; ++j) {
    mx[j] = 0.f;
    #pragma unroll
    for (int k = 0; k < K_TH; ++k) mx[j] += al[k] * inv * tmv[k][j];
  }
  float pm = 0.f;
  #pragma unroll
  for (int j = 0; j < 4; ++j) pm += mx[j] * wg2[j];
  const float gate = sigmoid_f(gh + block_sum(pm, red, t));
  const int inj = inject[s];
  #pragma unroll
  for (int j = 0; j < 4; ++j) {
    const float e = inj ? (gate * mx[j] + (1.f - gate) * hv[j]) : hv[j];
    enhB[(size_t)m * H_SZ + t + 256 * j] = (bf16_t)e;
  }
}

// ---------------- shifted CE loss from fused partials ----------------
__global__ void __launch_bounds__(256) loss_kernel(
    const float* __restrict__ Z2, const float* __restrict__ picked,
    float* __restrict__ out_loss) {
  const int t = threadIdx.x;
  float acc = 0.f;
  for (int i = t; i < (S_SZ - 1) * B_SZ; i += 256) {
    const int b = i / (S_SZ - 1), s2 = i % (S_SZ - 1);
    const int m = b * S_SZ + s2;
    acc += __logf(Z2[m]) - picked[m];
  }
  __shared__ float red[4];
  acc = block_sum(acc, red, t);
  if (t == 0) out_loss[0] = acc / (float)((S_SZ - 1) * B_SZ);
}

extern "C" void kernel_launch(void* const* d_in, const int* in_sizes, int n_in,
                              void* d_out, int out_size, void* d_ws, size_t ws_size,
                              hipStream_t stream) {
  const int*   ids    = (const int*)  d_in[0];
  const int*   labels = (const int*)  d_in[1];
  const float* embed  = (const float*)d_in[2];
  const float* W1     = (const float*)d_in[3];
  const float* b1     = (const float*)d_in[4];
  const float* lm     = (const float*)d_in[5];
  const float* Wg     = (const float*)d_in[6];
  const float* thE    = (const float*)d_in[7];
  const float* tpos   = (const float*)d_in[8];
  const float* wsc    = (const float*)d_in[9];
  const float* wgt    = (const float*)d_in[10];
  float* out = (float*)d_out;

  char* p = (char*)d_ws;
  auto carve = [&p](size_t bytes) {
    char* r = p;
    p += (bytes + 255) & ~(size_t)255;
    return r;
  };
  bf16_t* lmT   = (bf16_t*)carve((size_t)V_SZ * H_SZ * sizeof(bf16_t));  // (V,H)
  bf16_t* W1T   = (bf16_t*)carve((size_t)H_SZ * H_SZ * sizeof(bf16_t));
  bf16_t* WgT   = (bf16_t*)carve((size_t)H_SZ * H_SZ * sizeof(bf16_t));
  bf16_t* X0    = (bf16_t*)carve((size_t)M_SZ * H_SZ * sizeof(bf16_t));
  bf16_t* hidB  = (bf16_t*)carve((size_t)M_SZ * H_SZ * sizeof(bf16_t));
  bf16_t* enhB  = (bf16_t*)carve((size_t)M_SZ * H_SZ * sizeof(bf16_t));
  float*  hidF  = (float*) carve((size_t)M_SZ * H_SZ * sizeof(float));
  float*  gF    = (float*) carve((size_t)M_SZ * H_SZ * sizeof(float));
  float*  part  = (float*) carve(3 * M_SZ * sizeof(float));  // pZ, pS, Z2
  float*  picked= (float*) carve(M_SZ * sizeof(float));
  int*    inj   = (int*)   carve(S_SZ * sizeof(int));
  float* pZ = part, *pS = part + M_SZ, *Z2 = part + 2 * M_SZ;

  // weight prep
  transpose_cast_kernel<<<dim3(V_SZ / 64, H_SZ / 64), 256, 0, stream>>>(lm, lmT, H_SZ, V_SZ);
  transpose_cast_kernel<<<dim3(H_SZ / 64, H_SZ / 64), 256, 0, stream>>>(W1, W1T, H_SZ, H_SZ);
  transpose_cast_kernel<<<dim3(H_SZ / 64, H_SZ / 64), 256, 0, stream>>>(Wg, WgT, H_SZ, H_SZ);
  gather_cast_kernel<<<M_SZ * H_SZ / 4 / 256, 256, 0, stream>>>(ids, embed, X0);
  hipMemsetAsync(part, 0, 3 * M_SZ * sizeof(float), stream);

  // base model (64-tiles: 16x16 = 256 blocks)
  gemm_bt<1, 2><<<256, 256, 0, stream>>>(X0, W1T, hidF, hidB, b1, nullptr,
                                         nullptr, nullptr, nullptr, 16, 16, H_SZ);
  gemm_bt<2, 2><<<256, 256, 0, stream>>>(hidB, WgT, gF, nullptr, nullptr, nullptr,
                                         nullptr, nullptr, nullptr, 16, 16, H_SZ);
  // base logits -> entropy partials only (no logits materialization)
  gemm_bt<3, 4><<<2048, 256, 0, stream>>>(hidB, lmT, nullptr, nullptr, nullptr, nullptr,
                                          pZ, pS, nullptr, 8, 250, V_SZ);
  inject_kernel<<<1, 256, 0, stream>>>(pZ, pS, inj);
  mix_kernel<<<M_SZ, 256, 0, stream>>>(hidF, gF, thE, tpos, wsc, wgt, inj, enhB);

  // final logits (+ lse partials + label gather) + loss
  gemm_bt<4, 4><<<2048, 256, 0, stream>>>(enhB, lmT, out, nullptr, nullptr, labels,
                                          Z2, nullptr, picked, 8, 250, V_SZ);
  loss_kernel<<<1, 256, 0, stream>>>(Z2, picked, out + (size_t)M_SZ * V_SZ);
}